// Round 4
// baseline (330.647 us; speedup 1.0000x reference)
//
#include <hip/hip_runtime.h>
#include <math.h>

#define H   2048
#define SW  256
#define SD  200
#define GIN (H + SW)   // 2304
#define G3H (3 * H)    // 6144
#define OO  128

// ws float offsets. uints ctr[0]=stack_done, ctr[1]=gemv_done live in floats 0..7.
#define STOP_OFF 8
#define GI_OFF   512
#define GH_OFF   (GI_OFF + G3H)   // 6656

// block role partition (dispatch order follows dependency topology)
#define NB_SIN  64
#define NB_ELEM 50
#define NB_GH   384
#define NB_GI   384
#define NB_OUT  32
#define B_ELEM  NB_SIN                    // 64
#define B_GH    (B_ELEM + NB_ELEM)        // 114
#define B_GI    (B_GH + NB_GH)            // 498
#define B_OUT   (B_GI + NB_GI)            // 882
#define NBLK    (B_OUT + NB_OUT)          // 914

__device__ __forceinline__ float wave_reduce(float v) {
#pragma unroll
    for (int off = 32; off > 0; off >>= 1)
        v += __shfl_down(v, off, 64);
    return v;
}

__device__ __forceinline__ float sigmoidf(float x) {
    return 1.f / (1.f + expf(-x));
}

__device__ __forceinline__ float dot4(float4 a, float4 b) {
    return a.x * b.x + a.y * b.y + a.z * b.z + a.w * b.w;
}

__device__ __forceinline__ unsigned ld_acq(const unsigned* p) {
    return __hip_atomic_load(p, __ATOMIC_ACQUIRE, __HIP_MEMORY_SCOPE_AGENT);
}

__device__ __forceinline__ void signal_done(unsigned* c) {
    __threadfence();  // L2 writeback to coherence point (covers whole block's stores)
    __hip_atomic_fetch_add(c, 1u, __ATOMIC_RELEASE, __HIP_MEMORY_SCOPE_AGENT);
}

__global__ __launch_bounds__(256, 4) void k_fused(
        const float* __restrict__ hidden,
        const float* __restrict__ stack,
        const float* __restrict__ emb,
        const int*   __restrict__ inp,
        const float* __restrict__ Wc, const float* __restrict__ bc,
        const float* __restrict__ Ws, const float* __restrict__ bs,
        const float* __restrict__ W_ih, const float* __restrict__ b_ih,
        const float* __restrict__ W_hh, const float* __restrict__ b_hh,
        const float* __restrict__ Wd, const float* __restrict__ bd,
        float* __restrict__ ws,
        float* __restrict__ d_out) {
    __shared__ __align__(16) float lds[H];   // vec stage (gemv) / h_new (out) / sc (stack)
    unsigned* ctr = (unsigned*)ws;
    float* out_stack = d_out + OO + H;
    int b = blockIdx.x;
    int tid = threadIdx.x;
    int wave = tid >> 6, lane = tid & 63;

    if (b < B_GH) {
        // ---- stack roles: ctrl softmax (redundant per block, L2-hot) ----
        if (tid < 64) {
            float c0 = 0.f, c1 = 0.f, c2 = 0.f;
            for (int k = tid; k < H; k += 64) {
                float hv = hidden[k];
                c0 += hv * Wc[k];
                c1 += hv * Wc[H + k];
                c2 += hv * Wc[2 * H + k];
            }
            c0 = wave_reduce(c0); c1 = wave_reduce(c1); c2 = wave_reduce(c2);
            if (tid == 0) {
                c0 += bc[0]; c1 += bc[1]; c2 += bc[2];
                float m = fmaxf(c0, fmaxf(c1, c2));
                float e0 = expf(c0 - m), e1 = expf(c1 - m), e2 = expf(c2 - m);
                float inv = 1.f / (e0 + e1 + e2);
                lds[0] = e0 * inv;  // push
                lds[1] = e1 * inv;  // pop
                lds[2] = e2 * inv;  // noop
            }
        }
        __syncthreads();
        float a_push = lds[0], a_pop = lds[1], a_noop = lds[2];
        if (b < B_ELEM) {
            // ---- s_in rows (1/wave) + new_stack row 0 + stack_top -> ws ----
            int row = b * 4 + wave;
            const float4* h4 = (const float4*)hidden;
            const float4* w4 = (const float4*)(Ws + row * H);
            float sum = 0.f;
#pragma unroll
            for (int i = 0; i < 8; ++i)
                sum += dot4(h4[lane + i * 64], w4[lane + i * 64]);
            sum = wave_reduce(sum);
            if (lane == 0) {
                float s = tanhf(sum + bs[row]);
                float top = a_noop * stack[row] + a_push * s + a_pop * stack[SW + row];
                ws[STOP_OFF + row] = top;
                out_stack[row] = top;
            }
            __syncthreads();
            if (tid == 0) signal_done(&ctr[0]);
        } else {
            // ---- new_stack rows 1..199 elementwise (no consumers in-kernel) ----
            int rbase = 1 + (b - B_ELEM) * 4;
#pragma unroll
            for (int r = 0; r < 4; ++r) {
                int row = rbase + r;
                if (row >= SD) break;
                int idx = row * SW + tid;
                float dn = (row < SD - 1) ? stack[idx + SW] : 0.f;
                out_stack[idx] = a_noop * stack[idx] + a_push * stack[idx - SW] + a_pop * dn;
            }
        }
        return;
    }

    if (b < B_OUT) {
        // ---- GEMV: gh = hidden @ W_hh^T + b_hh   (no deps, streams immediately)
        // ----        gi = [emb;stack_top] @ W_ih^T + b_ih (emb part first, then spin)
        bool is_gh = (b < B_GI);
        int idx = is_gh ? (b - B_GH) : (b - B_GI);
        const float* srcv = is_gh ? hidden : (emb + (long)inp[0] * H);
        {   // stage 2048-float vector to LDS
            float4* l4 = (float4*)lds;
            const float4* s4 = (const float4*)srcv;
            l4[tid] = s4[tid];
            l4[tid + 256] = s4[tid + 256];
        }
        __syncthreads();
        int K = is_gh ? H : GIN;
        int rbase = idx * 16 + wave * 4;
        const float* W    = is_gh ? W_hh : W_ih;
        const float* bias = is_gh ? b_hh : b_ih;
        const float4* v4 = (const float4*)lds;
        const float4* w0 = (const float4*)(W + (long)(rbase + 0) * K);
        const float4* w1 = (const float4*)(W + (long)(rbase + 1) * K);
        const float4* w2 = (const float4*)(W + (long)(rbase + 2) * K);
        const float4* w3 = (const float4*)(W + (long)(rbase + 3) * K);
        float s0 = 0.f, s1 = 0.f, s2 = 0.f, s3 = 0.f;
#pragma unroll
        for (int u = 0; u < 4; ++u) {       // 512 float4s, unroll x2 pairs
            int i = lane + u * 128, j = i + 64;
            float4 a0 = v4[i], a1 = v4[j];
            float4 b00 = w0[i], b01 = w0[j];
            float4 b10 = w1[i], b11 = w1[j];
            float4 b20 = w2[i], b21 = w2[j];
            float4 b30 = w3[i], b31 = w3[j];
            s0 += dot4(a0, b00) + dot4(a1, b01);
            s1 += dot4(a0, b10) + dot4(a1, b11);
            s2 += dot4(a0, b20) + dot4(a1, b21);
            s3 += dot4(a0, b30) + dot4(a1, b31);
        }
        if (!is_gh) {
            // stack_top tail: wait for s_in producers (long since done), then 64 float4s
            if (tid == 0) {
                while (ld_acq(&ctr[0]) != (unsigned)NB_SIN) __builtin_amdgcn_s_sleep(2);
                __threadfence();
            }
            __syncthreads();
            const float4* st4 = (const float4*)(ws + STOP_OFF);
            float4 a = st4[lane];
            s0 += dot4(a, w0[512 + lane]);
            s1 += dot4(a, w1[512 + lane]);
            s2 += dot4(a, w2[512 + lane]);
            s3 += dot4(a, w3[512 + lane]);
        }
        s0 = wave_reduce(s0);
        s1 = wave_reduce(s1);
        s2 = wave_reduce(s2);
        s3 = wave_reduce(s3);
        float* dst = ws + (is_gh ? GH_OFF : GI_OFF);
        if (lane == 0) {
            dst[rbase + 0] = s0 + bias[rbase + 0];
            dst[rbase + 1] = s1 + bias[rbase + 1];
            dst[rbase + 2] = s2 + bias[rbase + 2];
            dst[rbase + 3] = s3 + bias[rbase + 3];
        }
        __syncthreads();
        if (tid == 0) signal_done(&ctr[1]);
        return;
    }

    // ---- out blocks: spin on all 768 gemv producers, then gates + Wd ----
    {
        int idx = b - B_OUT;              // 0..31
        if (tid == 0) {
            while (ld_acq(&ctr[1]) != (unsigned)(NB_GH + NB_GI)) __builtin_amdgcn_s_sleep(2);
            __threadfence();
        }
        __syncthreads();
        const float* gi = ws + GI_OFF;
        const float* gh = ws + GH_OFF;
        for (int i = tid; i < H; i += 256) {
            float r = sigmoidf(gi[i] + gh[i]);
            float z = sigmoidf(gi[H + i] + gh[H + i]);
            float n = tanhf(gi[2 * H + i] + r * gh[2 * H + i]);
            float v = (1.f - z) * n + z * hidden[i];
            lds[i] = v;
            if (idx == 0) d_out[OO + i] = v;
        }
        __syncthreads();
        int row = idx * 4 + wave;         // 128 rows
        const float4* h4 = (const float4*)lds;
        const float4* w4 = (const float4*)(Wd + (long)row * H);
        float sum = 0.f;
#pragma unroll
        for (int i = 0; i < 8; ++i)
            sum += dot4(h4[lane + i * 64], w4[lane + i * 64]);
        sum = wave_reduce(sum);
        if (lane == 0) d_out[row] = sum + bd[row];
    }
}

extern "C" void kernel_launch(void* const* d_in, const int* in_sizes, int n_in,
                              void* d_out, int out_size, void* d_ws, size_t ws_size,
                              hipStream_t stream) {
    const int*   inp    = (const int*)d_in[0];
    const float* hidden = (const float*)d_in[1];
    const float* stack  = (const float*)d_in[2];
    const float* emb    = (const float*)d_in[3];
    const float* Wc     = (const float*)d_in[4];
    const float* bc     = (const float*)d_in[5];
    const float* Ws     = (const float*)d_in[6];
    const float* bs     = (const float*)d_in[7];
    const float* W_ih   = (const float*)d_in[8];
    const float* b_ih   = (const float*)d_in[9];
    const float* W_hh   = (const float*)d_in[10];
    const float* b_hh   = (const float*)d_in[11];
    const float* Wd     = (const float*)d_in[12];
    const float* bd     = (const float*)d_in[13];
    float* out = (float*)d_out;
    float* ws  = (float*)d_ws;

    // zero the two spin counters (ws is poisoned 0xAA before every launch)
    hipMemsetAsync(ws, 0, 32, stream);
    k_fused<<<NBLK, 256, 0, stream>>>(hidden, stack, emb, inp, Wc, bc, Ws, bs,
                                      W_ih, b_ih, W_hh, b_hh, Wd, bd, ws, out);
}

// Round 5
// 200.521 us; speedup vs baseline: 1.6489x; 1.6489x over previous
//
#include <hip/hip_runtime.h>
#include <math.h>

#define H   2048
#define SW  256
#define SD  200
#define GIN (H + SW)   // 2304
#define G3H (3 * H)    // 6144
#define OO  128

// ws float offsets. uints ctr[0]=stack_done, ctr[1]=gemv_done live in floats 0..7.
#define STOP_OFF 8
#define GI_OFF   512
#define GH_OFF   (GI_OFF + G3H)   // 6656

// block role partition (dispatch order follows dependency topology)
#define NB_SIN  64
#define NB_ELEM 50
#define NB_GH   384
#define NB_GI   384
#define NB_OUT  32
#define B_ELEM  NB_SIN                    // 64
#define B_GH    (B_ELEM + NB_ELEM)        // 114
#define B_GI    (B_GH + NB_GH)            // 498
#define B_OUT   (B_GI + NB_GI)            // 882
#define NBLK    (B_OUT + NB_OUT)          // 914

__device__ __forceinline__ float wave_reduce(float v) {
#pragma unroll
    for (int off = 32; off > 0; off >>= 1)
        v += __shfl_down(v, off, 64);
    return v;
}

__device__ __forceinline__ float sigmoidf(float x) {
    return 1.f / (1.f + expf(-x));
}

__device__ __forceinline__ float dot4(float4 a, float4 b) {
    return a.x * b.x + a.y * b.y + a.z * b.z + a.w * b.w;
}

// --- zero-cache-maintenance cross-XCD protocol -----------------------------
// Relaxed agent-scope ops only: stores write through to the coherence point,
// loads bypass the (non-coherent) local L2. No buffer_inv / buffer_wbl2 is
// ever emitted (those were the R4 killer: acquire-per-poll = continuous L2
// tag-walk invalidations that collapsed streaming BW to 260 GB/s).
// Producer ordering: __syncthreads() pre-barrier s_waitcnt vmcnt(0) drains
// the data stores before the counter FAA is issued.
__device__ __forceinline__ unsigned ld_rlx_u32(const unsigned* p) {
    return __hip_atomic_load(p, __ATOMIC_RELAXED, __HIP_MEMORY_SCOPE_AGENT);
}
__device__ __forceinline__ float ld_rlx_f32(const float* p) {
    return __hip_atomic_load(p, __ATOMIC_RELAXED, __HIP_MEMORY_SCOPE_AGENT);
}
__device__ __forceinline__ void st_rlx_f32(float* p, float v) {
    __hip_atomic_store(p, v, __ATOMIC_RELAXED, __HIP_MEMORY_SCOPE_AGENT);
}
__device__ __forceinline__ void faa_rlx(unsigned* p) {
    __hip_atomic_fetch_add(p, 1u, __ATOMIC_RELAXED, __HIP_MEMORY_SCOPE_AGENT);
}

__global__ __launch_bounds__(256, 4) void k_fused(
        const float* __restrict__ hidden,
        const float* __restrict__ stack,
        const float* __restrict__ emb,
        const int*   __restrict__ inp,
        const float* __restrict__ Wc, const float* __restrict__ bc,
        const float* __restrict__ Ws, const float* __restrict__ bs,
        const float* __restrict__ W_ih, const float* __restrict__ b_ih,
        const float* __restrict__ W_hh, const float* __restrict__ b_hh,
        const float* __restrict__ Wd, const float* __restrict__ bd,
        float* __restrict__ ws,
        float* __restrict__ d_out) {
    __shared__ __align__(16) float lds[H];   // vec stage (gemv) / h_new (out) / sc (stack)
    unsigned* ctr = (unsigned*)ws;
    float* out_stack = d_out + OO + H;
    int b = blockIdx.x;
    int tid = threadIdx.x;
    int wave = tid >> 6, lane = tid & 63;

    if (b < B_GH) {
        // ---- stack roles: ctrl softmax (redundant per block, L2-hot) ----
        if (tid < 64) {
            float c0 = 0.f, c1 = 0.f, c2 = 0.f;
            for (int k = tid; k < H; k += 64) {
                float hv = hidden[k];
                c0 += hv * Wc[k];
                c1 += hv * Wc[H + k];
                c2 += hv * Wc[2 * H + k];
            }
            c0 = wave_reduce(c0); c1 = wave_reduce(c1); c2 = wave_reduce(c2);
            if (tid == 0) {
                c0 += bc[0]; c1 += bc[1]; c2 += bc[2];
                float m = fmaxf(c0, fmaxf(c1, c2));
                float e0 = expf(c0 - m), e1 = expf(c1 - m), e2 = expf(c2 - m);
                float inv = 1.f / (e0 + e1 + e2);
                lds[0] = e0 * inv;  // push
                lds[1] = e1 * inv;  // pop
                lds[2] = e2 * inv;  // noop
            }
        }
        __syncthreads();
        float a_push = lds[0], a_pop = lds[1], a_noop = lds[2];
        if (b < B_ELEM) {
            // ---- s_in rows (1/wave) + new_stack row 0 + stack_top -> ws ----
            int row = b * 4 + wave;
            const float4* h4 = (const float4*)hidden;
            const float4* w4 = (const float4*)(Ws + row * H);
            float sum = 0.f;
#pragma unroll
            for (int i = 0; i < 8; ++i)
                sum += dot4(h4[lane + i * 64], w4[lane + i * 64]);
            sum = wave_reduce(sum);
            if (lane == 0) {
                float s = tanhf(sum + bs[row]);
                float top = a_noop * stack[row] + a_push * s + a_pop * stack[SW + row];
                st_rlx_f32(ws + STOP_OFF + row, top);   // write-through
                out_stack[row] = top;
            }
            __syncthreads();                // drains the lane-0 stores (vmcnt)
            if (tid == 0) faa_rlx(&ctr[0]);
        } else {
            // ---- new_stack rows 1..199 elementwise (no in-kernel consumers) ----
            int rbase = 1 + (b - B_ELEM) * 4;
#pragma unroll
            for (int r = 0; r < 4; ++r) {
                int row = rbase + r;
                if (row >= SD) break;
                int idx = row * SW + tid;
                float dn = (row < SD - 1) ? stack[idx + SW] : 0.f;
                out_stack[idx] = a_noop * stack[idx] + a_push * stack[idx - SW] + a_pop * dn;
            }
        }
        return;
    }

    if (b < B_OUT) {
        // ---- GEMV: gh = hidden @ W_hh^T + b_hh   (no deps, streams immediately)
        // ----        gi = [emb;stack_top] @ W_ih^T + b_ih (emb part first, then poll)
        bool is_gh = (b < B_GI);
        int idx = is_gh ? (b - B_GH) : (b - B_GI);
        const float* srcv = is_gh ? hidden : (emb + (long)inp[0] * H);
        {   // stage 2048-float vector to LDS
            float4* l4 = (float4*)lds;
            const float4* s4 = (const float4*)srcv;
            l4[tid] = s4[tid];
            l4[tid + 256] = s4[tid + 256];
        }
        __syncthreads();
        int K = is_gh ? H : GIN;
        int rbase = idx * 16 + wave * 4;
        const float* W    = is_gh ? W_hh : W_ih;
        const float* bias = is_gh ? b_hh : b_ih;
        const float4* v4 = (const float4*)lds;
        const float4* w0 = (const float4*)(W + (long)(rbase + 0) * K);
        const float4* w1 = (const float4*)(W + (long)(rbase + 1) * K);
        const float4* w2 = (const float4*)(W + (long)(rbase + 2) * K);
        const float4* w3 = (const float4*)(W + (long)(rbase + 3) * K);
        float s0 = 0.f, s1 = 0.f, s2 = 0.f, s3 = 0.f;
#pragma unroll
        for (int u = 0; u < 4; ++u) {       // 512 float4s, unroll x2 pairs
            int i = lane + u * 128, j = i + 64;
            float4 a0 = v4[i], a1 = v4[j];
            float4 b00 = w0[i], b01 = w0[j];
            float4 b10 = w1[i], b11 = w1[j];
            float4 b20 = w2[i], b21 = w2[j];
            float4 b30 = w3[i], b31 = w3[j];
            s0 += dot4(a0, b00) + dot4(a1, b01);
            s1 += dot4(a0, b10) + dot4(a1, b11);
            s2 += dot4(a0, b20) + dot4(a1, b21);
            s3 += dot4(a0, b30) + dot4(a1, b31);
        }
        if (!is_gh) {
            // stack_top tail: relaxed-poll (no invalidates), then 64 float4-equiv
            if (tid == 0) {
                while (ld_rlx_u32(&ctr[0]) != (unsigned)NB_SIN)
                    __builtin_amdgcn_s_sleep(4);
            }
            __syncthreads();
            const float* st = ws + STOP_OFF;
            float4 a;
            a.x = ld_rlx_f32(st + 4 * lane + 0);
            a.y = ld_rlx_f32(st + 4 * lane + 1);
            a.z = ld_rlx_f32(st + 4 * lane + 2);
            a.w = ld_rlx_f32(st + 4 * lane + 3);
            s0 += dot4(a, w0[512 + lane]);
            s1 += dot4(a, w1[512 + lane]);
            s2 += dot4(a, w2[512 + lane]);
            s3 += dot4(a, w3[512 + lane]);
        }
        s0 = wave_reduce(s0);
        s1 = wave_reduce(s1);
        s2 = wave_reduce(s2);
        s3 = wave_reduce(s3);
        float* dst = ws + (is_gh ? GH_OFF : GI_OFF);
        if (lane == 0) {
            st_rlx_f32(dst + rbase + 0, s0 + bias[rbase + 0]);
            st_rlx_f32(dst + rbase + 1, s1 + bias[rbase + 1]);
            st_rlx_f32(dst + rbase + 2, s2 + bias[rbase + 2]);
            st_rlx_f32(dst + rbase + 3, s3 + bias[rbase + 3]);
        }
        __syncthreads();                    // drains the lane-0 stores (vmcnt)
        if (tid == 0) faa_rlx(&ctr[1]);
        return;
    }

    // ---- out blocks: relaxed-poll all 768 gemv producers, then gates + Wd ----
    {
        int idx = b - B_OUT;              // 0..31
        if (tid == 0) {
            while (ld_rlx_u32(&ctr[1]) != (unsigned)(NB_GH + NB_GI))
                __builtin_amdgcn_s_sleep(4);
        }
        __syncthreads();
        const float* gi = ws + GI_OFF;
        const float* gh = ws + GH_OFF;
        for (int i = tid; i < H; i += 256) {
            float gir = ld_rlx_f32(gi + i),         ghr = ld_rlx_f32(gh + i);
            float giz = ld_rlx_f32(gi + H + i),     ghz = ld_rlx_f32(gh + H + i);
            float gin = ld_rlx_f32(gi + 2 * H + i), ghn = ld_rlx_f32(gh + 2 * H + i);
            float r = sigmoidf(gir + ghr);
            float z = sigmoidf(giz + ghz);
            float n = tanhf(gin + r * ghn);
            float v = (1.f - z) * n + z * hidden[i];
            lds[i] = v;
            if (idx == 0) d_out[OO + i] = v;
        }
        __syncthreads();
        int row = idx * 4 + wave;         // 128 rows
        const float4* h4 = (const float4*)lds;
        const float4* w4 = (const float4*)(Wd + (long)row * H);
        float sum = 0.f;
#pragma unroll
        for (int i = 0; i < 8; ++i)
            sum += dot4(h4[lane + i * 64], w4[lane + i * 64]);
        sum = wave_reduce(sum);
        if (lane == 0) d_out[row] = sum + bd[row];
    }
}

extern "C" void kernel_launch(void* const* d_in, const int* in_sizes, int n_in,
                              void* d_out, int out_size, void* d_ws, size_t ws_size,
                              hipStream_t stream) {
    const int*   inp    = (const int*)d_in[0];
    const float* hidden = (const float*)d_in[1];
    const float* stack  = (const float*)d_in[2];
    const float* emb    = (const float*)d_in[3];
    const float* Wc     = (const float*)d_in[4];
    const float* bc     = (const float*)d_in[5];
    const float* Ws     = (const float*)d_in[6];
    const float* bs     = (const float*)d_in[7];
    const float* W_ih   = (const float*)d_in[8];
    const float* b_ih   = (const float*)d_in[9];
    const float* W_hh   = (const float*)d_in[10];
    const float* b_hh   = (const float*)d_in[11];
    const float* Wd     = (const float*)d_in[12];
    const float* bd     = (const float*)d_in[13];
    float* out = (float*)d_out;
    float* ws  = (float*)d_ws;

    // zero the two spin counters (ws is poisoned 0xAA before every launch)
    hipMemsetAsync(ws, 0, 32, stream);
    k_fused<<<NBLK, 256, 0, stream>>>(hidden, stack, emb, inp, Wc, bc, Ws, bs,
                                      W_ih, b_ih, W_hh, b_hh, Wd, bd, ws, out);
}